// Round 18
// baseline (236.799 us; speedup 1.0000x reference)
//
#include <hip/hip_runtime.h>
#include <hip/hip_bf16.h>
#include <math.h>

#define N 8192
#define ZD 128
#define NTILE 64            // N / 128
#define NUPPER 2080         // NTILE*(NTILE+1)/2 (= 8 * 260)

typedef __attribute__((ext_vector_type(8))) _Float16 f16x8;
typedef __attribute__((ext_vector_type(4))) float f32x4;

__device__ __forceinline__ int tri_cum(int ti) {   // tiles before row ti
    return (ti * (2 * NTILE + 1 - ti)) / 2;        // ti*(129-ti)/2
}

__device__ __forceinline__ void tile_decode(int t, int& ti, int& tj) {
    int est = (int)((129.0f - sqrtf(16641.0f - 8.0f * (float)t)) * 0.5f);
    if (est < 0) est = 0;
    while (tri_cum(est) > t) --est;
    while (tri_cum(est + 1) <= t) ++est;
    ti = est;
    tj = est + (t - tri_cum(est));
}

// ---------------------------------------------------------------------------
// k1: Z = relu(h @ W1 + b1) @ W2 + b2 (fp32 math), stored as f16.
// Also initializes sums[i] = 1.0 (the fill_diagonal(1) contribution).
// ---------------------------------------------------------------------------
__global__ __launch_bounds__(256) void k1_mlp(
    const float* __restrict__ h, const float* __restrict__ W1,
    const float* __restrict__ b1, const float* __restrict__ W2,
    const float* __restrict__ b2, _Float16* __restrict__ Zf,
    float* __restrict__ sums)
{
    __shared__ float W1s[64][65];
    __shared__ float W2s[64][129];
    __shared__ float hs[32][68];
    __shared__ float Ts[32][68];
    __shared__ float b1s[64];
    __shared__ float b2s[128];
    const int tid = threadIdx.x;
    const int row0 = blockIdx.x * 32;

    if (tid < 32) sums[row0 + tid] = 1.0f;

    for (int e = tid; e < 64 * 64; e += 256) W1s[e >> 6][e & 63] = W1[e];
    for (int e = tid; e < 64 * 128; e += 256) W2s[e >> 7][e & 127] = W2[e];
    for (int e = tid; e < 32 * 64; e += 256) hs[e >> 6][e & 63] = h[(size_t)row0 * 64 + e];
    if (tid < 64) b1s[tid] = b1[tid];
    if (tid < 128) b2s[tid] = b2[tid];
    __syncthreads();

    // layer 1: 32x64 outputs, 8 rows per thread, shared weight broadcast
    {
        const int c = tid & 63;
        const int r0 = (tid >> 6) * 8;
        float s[8];
        #pragma unroll
        for (int j = 0; j < 8; ++j) s[j] = b1s[c];
        #pragma unroll
        for (int k0 = 0; k0 < 64; k0 += 4) {
            const float w0 = W1s[k0 + 0][c], w1 = W1s[k0 + 1][c];
            const float w2 = W1s[k0 + 2][c], w3 = W1s[k0 + 3][c];
            #pragma unroll
            for (int j = 0; j < 8; ++j) {
                f32x4 hv = *(const f32x4*)&hs[r0 + j][k0];
                s[j] = fmaf(hv[0], w0, s[j]);
                s[j] = fmaf(hv[1], w1, s[j]);
                s[j] = fmaf(hv[2], w2, s[j]);
                s[j] = fmaf(hv[3], w3, s[j]);
            }
        }
        #pragma unroll
        for (int j = 0; j < 8; ++j) Ts[r0 + j][c] = fmaxf(s[j], 0.0f);
    }
    __syncthreads();

    // layer 2: 32x128 outputs, 16 rows per thread
    {
        const int c = tid & 127;
        const int r0 = (tid >> 7) * 16;
        float s[16];
        #pragma unroll
        for (int j = 0; j < 16; ++j) s[j] = b2s[c];
        #pragma unroll
        for (int k0 = 0; k0 < 64; k0 += 4) {
            const float w0 = W2s[k0 + 0][c], w1 = W2s[k0 + 1][c];
            const float w2 = W2s[k0 + 2][c], w3 = W2s[k0 + 3][c];
            #pragma unroll
            for (int j = 0; j < 16; ++j) {
                f32x4 tv = *(const f32x4*)&Ts[r0 + j][k0];
                s[j] = fmaf(tv[0], w0, s[j]);
                s[j] = fmaf(tv[1], w1, s[j]);
                s[j] = fmaf(tv[2], w2, s[j]);
                s[j] = fmaf(tv[3], w3, s[j]);
            }
        }
        #pragma unroll
        for (int j = 0; j < 16; ++j)
            Zf[(size_t)(row0 + r0 + j) * ZD + c] = (_Float16)s[j];
    }
}

// ---------------------------------------------------------------------------
// k3: 2080 upper tiles (1-D grid, bijective XCD swizzle), 128x128 per block,
// 4 waves, 3 blocks/CU (natural VGPR, no cap -- caps spill: R12/R13/R16).
// Single-pass f16 MFMA GEMM, operands direct from L2. Epilogue: LDS-staged
// in two 64-col halves; logits/vtile use PLAIN stores (complete at L2
// ~200cy -> cheap barrier drains; nt stores only completed at HBM ~900cy).
// Noise loads stay nontemporal (read-once). Sums via in-wave shfl
// reductions -> rs1/cs2 plain stores, one barrier, global atomics.
// ---------------------------------------------------------------------------
__global__ __launch_bounds__(256, 3) void k3_main(
    const _Float16* __restrict__ Zf, const float* __restrict__ noise,
    float* __restrict__ logits, unsigned char* __restrict__ vws,
    float* __restrict__ sums)
{
    int ti, tj;
    const int t = (blockIdx.x & 7) * (NUPPER / 8) + (blockIdx.x >> 3);  // XCD swizzle
    tile_decode(t, ti, tj);
    const bool diag = (ti == tj);

    __shared__ float T[128][65];       // 33280 B
    __shared__ float rs1[128];         // 512 B: row sums (owner-unique writes)
    __shared__ float cs2[4][128];      // 2048 B: per-wave col partials

    const int tid = threadIdx.x;
    const int lane = tid & 63;
    const int w = tid >> 6;
    const int wr = w >> 1, wc = w & 1;
    const int fr = lane & 15;     // fragment row (m/n within 16)
    const int kg = lane >> 4;     // k-group 0..3
    const int i0 = ti * 128, j0 = tj * 128;

    unsigned char* __restrict__ vtile = vws + (size_t)t * (128 * 128);

    const _Float16* Ap = Zf + (size_t)(i0 + wr * 64) * ZD;
    const _Float16* Bp = Zf + (size_t)(j0 + wc * 64) * ZD;

    f32x4 acc[4][4];
    #pragma unroll
    for (int mf = 0; mf < 4; ++mf)
        #pragma unroll
        for (int nf = 0; nf < 4; ++nf)
            acc[mf][nf] = (f32x4)0.0f;

    #pragma unroll
    for (int kc = 0; kc < 4; ++kc) {
        const int ko = kc * 32 + kg * 8;
        f16x8 a[4], b[4];
        #pragma unroll
        for (int mf = 0; mf < 4; ++mf) {
            size_t off = (size_t)(mf * 16 + fr) * ZD + ko;
            a[mf] = *(const f16x8*)(Ap + off);
            b[mf] = *(const f16x8*)(Bp + off);
        }
        #pragma unroll
        for (int mf = 0; mf < 4; ++mf)
            #pragma unroll
            for (int nf = 0; nf < 4; ++nf)
                acc[mf][nf] = __builtin_amdgcn_mfma_f32_16x16x32_f16(a[mf], b[nf], acc[mf][nf], 0, 0, 0);
    }

    // ---- epilogue in two 64-column halves ----
    const int cid = tid & 15;
    const int c4 = cid * 4;               // local col group within half
    const int rbase = tid >> 4;           // 0..15

    float rsacc[8];                       // per-thread row partials (both halves)
    #pragma unroll
    for (int it = 0; it < 8; ++it) rsacc[it] = 0.0f;

    #pragma unroll
    for (int half = 0; half < 2; ++half) {
        __syncthreads();   // previous half's T readers done
        if (wc == half) {
            #pragma unroll
            for (int mf = 0; mf < 4; ++mf)
                #pragma unroll
                for (int nf = 0; nf < 4; ++nf)
                    #pragma unroll
                    for (int r = 0; r < 4; ++r)
                        T[wr * 64 + mf * 16 + (lane >> 4) * 4 + r][nf * 16 + fr] = acc[mf][nf][r];
        }
        __syncthreads();

        f32x4 csum = (f32x4)0.0f;
        #pragma unroll
        for (int it = 0; it < 8; ++it) {
            const int r = rbase + it * 16;
            f32x4 L4 = *(const f32x4*)&T[r][c4];
            const size_t g = (size_t)(i0 + r) * N + j0 + half * 64 + c4;
            *(f32x4*)&logits[g] = L4;                       // plain store (L2)
            f32x4 u4 = __builtin_nontemporal_load((const f32x4*)&noise[g]);
            float rsum = 0.0f;
            unsigned q = 0;
            #pragma unroll
            for (int e = 0; e < 4; ++e) {
                float u = u4[e];
                float eps = fmaf(-0.9998f, u, 0.9999f);   // eps in [1e-4, 1-1e-4]
                float om  = fmaf( 0.9998f, u, 0.0001f);   // 1 - eps
                // v = sigmoid(log(eps)-log(1-eps)+L) = eps/(eps + (1-eps)e^{-L})
                float ex = __expf(-L4[e]);
                float v = eps / fmaf(om, ex, eps);
                if (diag && r >= half * 64 + c4 + e) v = 0.0f;  // strict upper
                q |= ((unsigned)(int)rintf(v * 255.0f)) << (8 * e);
                rsum += v;
                csum[e] += v;
            }
            *(unsigned*)&vtile[r * 128 + half * 64 + c4] = q;   // plain store
            rsacc[it] += rsum;            // register accumulate
        }
        // col partials: butterfly across the 4 row-groups sharing each col
        #pragma unroll
        for (int e = 0; e < 4; ++e) {
            float cv = csum[e];
            cv += __shfl_xor(cv, 16);
            cv += __shfl_xor(cv, 32);
            if (lane < 16)
                cs2[w][half * 64 + lane * 4 + e] = cv;
        }

        if (!diag) {
            #pragma unroll
            for (int it = 0; it < 8; ++it) {
                const int idx = tid + it * 256;     // 0..2047
                const int c = idx >> 5;             // 0..63
                const int m4 = (idx & 31) * 4;
                f32x4 o;
                o[0] = T[m4 + 0][c]; o[1] = T[m4 + 1][c];
                o[2] = T[m4 + 2][c]; o[3] = T[m4 + 3][c];
                *(f32x4*)&logits[(size_t)(j0 + half * 64 + c) * N + i0 + m4] = o;  // plain
            }
        }
    }

    // row sums: 16 cid-owners of row r are 16 consecutive lanes of one wave
    #pragma unroll
    for (int it = 0; it < 8; ++it) {
        float rv = rsacc[it];
        rv += __shfl_xor(rv, 1);
        rv += __shfl_xor(rv, 2);
        rv += __shfl_xor(rv, 4);
        rv += __shfl_xor(rv, 8);
        if (cid == 0)
            rs1[rbase + it * 16] = rv;
    }

    __syncthreads();

    if (tid < 128) {
        const float rowsum = rs1[tid];
        const float colsum = cs2[0][tid] + cs2[1][tid] + cs2[2][tid] + cs2[3][tid];
        if (diag) {
            atomicAdd(&sums[i0 + tid], rowsum + colsum);
        } else {
            atomicAdd(&sums[i0 + tid], rowsum);
            atomicAdd(&sums[j0 + tid], colsum);
        }
    }
}

// ---------------------------------------------------------------------------
// k5: adj[i,j] = v_u8/255 * d_i * d_j (from compact vtile), mirror to [j,i],
// diagonal = d_i^2. d = rsqrt(sums) recomputed per block (L2-resident sums).
// T is [col][row] with 68-stride for 16B-aligned vectorized mirror stores.
// PLAIN stores throughout (cheap barrier drain -- same mechanism as k3 R17).
// ---------------------------------------------------------------------------
__global__ __launch_bounds__(256, 4) void k5_norm(
    const unsigned char* __restrict__ vws, float* __restrict__ adj,
    const float* __restrict__ sums)
{
    int ti, tj;
    const int t = (blockIdx.x & 7) * (NUPPER / 8) + (blockIdx.x >> 3);  // XCD swizzle
    tile_decode(t, ti, tj);
    const bool diag = (ti == tj);
    __shared__ float T[128][68];
    __shared__ float drow[128], dcol[128];
    const int tid = threadIdx.x;
    const int i0 = ti * 128, j0 = tj * 128;

    const unsigned char* __restrict__ vtile = vws + (size_t)t * (128 * 128);

    if (tid < 128) drow[tid] = rsqrtf(sums[i0 + tid]);
    else dcol[tid - 128] = rsqrtf(sums[j0 + tid - 128]);
    __syncthreads();

    const float inv255 = 1.0f / 255.0f;
    #pragma unroll 4
    for (int it = 0; it < 16; ++it) {
        int w = tid + it * 256;
        int m = w >> 5;
        int n4 = (w & 31) << 2;
        unsigned q = __builtin_nontemporal_load((const unsigned*)&vtile[m * 128 + n4]);
        float dm = drow[m];
        f32x4 o;
        o[0] = (float)(q & 255)         * inv255 * dm * dcol[n4 + 0];
        o[1] = (float)((q >> 8) & 255)  * inv255 * dm * dcol[n4 + 1];
        o[2] = (float)((q >> 16) & 255) * inv255 * dm * dcol[n4 + 2];
        o[3] = (float)(q >> 24)         * inv255 * dm * dcol[n4 + 3];
        *(f32x4*)&adj[(size_t)(i0 + m) * N + j0 + n4] = o;   // plain store
        T[n4 + 0][m] = o[0]; T[n4 + 1][m] = o[1];
        T[n4 + 2][m] = o[2]; T[n4 + 3][m] = o[3];
    }
    __syncthreads();
    // mirror: adj[j0+c][i0+m4..m4+3] = T[c][m4..m4+3] (contiguous, 16B aligned)
    #pragma unroll 4
    for (int it = 0; it < 16; ++it) {
        int w = tid + it * 256;
        int c = w >> 5;
        int m4 = (w & 31) << 2;
        f32x4 o = *(const f32x4*)&T[c][m4];
        if (!diag) {
            *(f32x4*)&adj[(size_t)(j0 + c) * N + i0 + m4] = o;   // plain store
        } else {
            #pragma unroll
            for (int e = 0; e < 4; ++e)
                if (m4 + e < c)
                    adj[(size_t)(j0 + c) * N + i0 + m4 + e] = o[e];
        }
    }
    if (diag && tid < 128) {
        float dm = drow[tid];
        adj[(size_t)(i0 + tid) * N + i0 + tid] = dm * dm;
    }
}

// ---------------------------------------------------------------------------
extern "C" void kernel_launch(void* const* d_in, const int* in_sizes, int n_in,
                              void* d_out, int out_size, void* d_ws, size_t ws_size,
                              hipStream_t stream)
{
    const float* h     = (const float*)d_in[0];
    const float* W1    = (const float*)d_in[1];
    const float* b1    = (const float*)d_in[2];
    const float* W2    = (const float*)d_in[3];
    const float* b2    = (const float*)d_in[4];
    const float* noise = (const float*)d_in[5];

    float* adj    = (float*)d_out;                 // output 0: adj_norm [N,N]
    float* logits = adj + (size_t)N * N;           // output 1: adj_logits [N,N]

    _Float16* Zf       = (_Float16*)d_ws;                      // 2 MiB
    unsigned char* vws = (unsigned char*)(Zf + (size_t)N * ZD);// 2080*16384 u8 = 34 MiB
    float* sums        = (float*)(vws + (size_t)NUPPER * 128 * 128); // [N]

    k1_mlp<<<256, 256, 0, stream>>>(h, W1, b1, W2, b2, Zf, sums);
    k3_main<<<NUPPER, 256, 0, stream>>>(Zf, noise, logits, vws, sums);
    k5_norm<<<NUPPER, 256, 0, stream>>>(vws, adj, sums);
}

// Round 19
// 201.086 us; speedup vs baseline: 1.1776x; 1.1776x over previous
//
#include <hip/hip_runtime.h>
#include <hip/hip_bf16.h>
#include <math.h>

#define N 8192
#define ZD 128
#define NTILE 64            // N / 128
#define NUPPER 2080         // NTILE*(NTILE+1)/2 (= 8 * 260)

typedef __attribute__((ext_vector_type(8))) _Float16 f16x8;
typedef __attribute__((ext_vector_type(4))) float f32x4;

__device__ __forceinline__ int tri_cum(int ti) {   // tiles before row ti
    return (ti * (2 * NTILE + 1 - ti)) / 2;        // ti*(129-ti)/2
}

__device__ __forceinline__ void tile_decode(int t, int& ti, int& tj) {
    int est = (int)((129.0f - sqrtf(16641.0f - 8.0f * (float)t)) * 0.5f);
    if (est < 0) est = 0;
    while (tri_cum(est) > t) --est;
    while (tri_cum(est + 1) <= t) ++est;
    ti = est;
    tj = est + (t - tri_cum(est));
}

// ---------------------------------------------------------------------------
// k1: Z = relu(h @ W1 + b1) @ W2 + b2 (fp32 math), stored as f16.
// Also initializes sums[i] = 1.0 (the fill_diagonal(1) contribution).
// ---------------------------------------------------------------------------
__global__ __launch_bounds__(256) void k1_mlp(
    const float* __restrict__ h, const float* __restrict__ W1,
    const float* __restrict__ b1, const float* __restrict__ W2,
    const float* __restrict__ b2, _Float16* __restrict__ Zf,
    float* __restrict__ sums)
{
    __shared__ float W1s[64][65];
    __shared__ float W2s[64][129];
    __shared__ float hs[32][68];
    __shared__ float Ts[32][68];
    __shared__ float b1s[64];
    __shared__ float b2s[128];
    const int tid = threadIdx.x;
    const int row0 = blockIdx.x * 32;

    if (tid < 32) sums[row0 + tid] = 1.0f;

    for (int e = tid; e < 64 * 64; e += 256) W1s[e >> 6][e & 63] = W1[e];
    for (int e = tid; e < 64 * 128; e += 256) W2s[e >> 7][e & 127] = W2[e];
    for (int e = tid; e < 32 * 64; e += 256) hs[e >> 6][e & 63] = h[(size_t)row0 * 64 + e];
    if (tid < 64) b1s[tid] = b1[tid];
    if (tid < 128) b2s[tid] = b2[tid];
    __syncthreads();

    // layer 1: 32x64 outputs, 8 rows per thread, shared weight broadcast
    {
        const int c = tid & 63;
        const int r0 = (tid >> 6) * 8;
        float s[8];
        #pragma unroll
        for (int j = 0; j < 8; ++j) s[j] = b1s[c];
        #pragma unroll
        for (int k0 = 0; k0 < 64; k0 += 4) {
            const float w0 = W1s[k0 + 0][c], w1 = W1s[k0 + 1][c];
            const float w2 = W1s[k0 + 2][c], w3 = W1s[k0 + 3][c];
            #pragma unroll
            for (int j = 0; j < 8; ++j) {
                f32x4 hv = *(const f32x4*)&hs[r0 + j][k0];
                s[j] = fmaf(hv[0], w0, s[j]);
                s[j] = fmaf(hv[1], w1, s[j]);
                s[j] = fmaf(hv[2], w2, s[j]);
                s[j] = fmaf(hv[3], w3, s[j]);
            }
        }
        #pragma unroll
        for (int j = 0; j < 8; ++j) Ts[r0 + j][c] = fmaxf(s[j], 0.0f);
    }
    __syncthreads();

    // layer 2: 32x128 outputs, 16 rows per thread
    {
        const int c = tid & 127;
        const int r0 = (tid >> 7) * 16;
        float s[16];
        #pragma unroll
        for (int j = 0; j < 16; ++j) s[j] = b2s[c];
        #pragma unroll
        for (int k0 = 0; k0 < 64; k0 += 4) {
            const float w0 = W2s[k0 + 0][c], w1 = W2s[k0 + 1][c];
            const float w2 = W2s[k0 + 2][c], w3 = W2s[k0 + 3][c];
            #pragma unroll
            for (int j = 0; j < 16; ++j) {
                f32x4 tv = *(const f32x4*)&Ts[r0 + j][k0];
                s[j] = fmaf(tv[0], w0, s[j]);
                s[j] = fmaf(tv[1], w1, s[j]);
                s[j] = fmaf(tv[2], w2, s[j]);
                s[j] = fmaf(tv[3], w3, s[j]);
            }
        }
        #pragma unroll
        for (int j = 0; j < 16; ++j)
            Zf[(size_t)(row0 + r0 + j) * ZD + c] = (_Float16)s[j];
    }
}

// ---------------------------------------------------------------------------
// k3: 2080 upper tiles (1-D grid, bijective XCD swizzle), 128x128 per block,
// 4 waves, 3 blocks/CU (natural VGPR, no cap -- caps spill: R12/R13/R16).
// Single-pass f16 MFMA GEMM, operands direct from L2. Epilogue: LDS-staged
// in two 64-col halves; logits/vtile use PLAIN stores (complete at L2
// ~200cy -> cheap barrier drains at k3's 5 barriers; nt stores completed
// only at HBM ~900cy -- R17 proved plain wins HERE, R18 proved nt wins in
// k5). Noise loads stay nontemporal (read-once). v via
// v = eps * rcp(eps + (1-eps)e^{-L}) -- v_rcp_f32 + v_mul instead of the
// ~8-instr IEEE div sequence. Sums via in-wave shfl reductions ->
// rs1/cs2 plain stores, one barrier, global atomics.
// ---------------------------------------------------------------------------
__global__ __launch_bounds__(256, 3) void k3_main(
    const _Float16* __restrict__ Zf, const float* __restrict__ noise,
    float* __restrict__ logits, unsigned char* __restrict__ vws,
    float* __restrict__ sums)
{
    int ti, tj;
    const int t = (blockIdx.x & 7) * (NUPPER / 8) + (blockIdx.x >> 3);  // XCD swizzle
    tile_decode(t, ti, tj);
    const bool diag = (ti == tj);

    __shared__ float T[128][65];       // 33280 B
    __shared__ float rs1[128];         // 512 B: row sums (owner-unique writes)
    __shared__ float cs2[4][128];      // 2048 B: per-wave col partials

    const int tid = threadIdx.x;
    const int lane = tid & 63;
    const int w = tid >> 6;
    const int wr = w >> 1, wc = w & 1;
    const int fr = lane & 15;     // fragment row (m/n within 16)
    const int kg = lane >> 4;     // k-group 0..3
    const int i0 = ti * 128, j0 = tj * 128;

    unsigned char* __restrict__ vtile = vws + (size_t)t * (128 * 128);

    const _Float16* Ap = Zf + (size_t)(i0 + wr * 64) * ZD;
    const _Float16* Bp = Zf + (size_t)(j0 + wc * 64) * ZD;

    f32x4 acc[4][4];
    #pragma unroll
    for (int mf = 0; mf < 4; ++mf)
        #pragma unroll
        for (int nf = 0; nf < 4; ++nf)
            acc[mf][nf] = (f32x4)0.0f;

    #pragma unroll
    for (int kc = 0; kc < 4; ++kc) {
        const int ko = kc * 32 + kg * 8;
        f16x8 a[4], b[4];
        #pragma unroll
        for (int mf = 0; mf < 4; ++mf) {
            size_t off = (size_t)(mf * 16 + fr) * ZD + ko;
            a[mf] = *(const f16x8*)(Ap + off);
            b[mf] = *(const f16x8*)(Bp + off);
        }
        #pragma unroll
        for (int mf = 0; mf < 4; ++mf)
            #pragma unroll
            for (int nf = 0; nf < 4; ++nf)
                acc[mf][nf] = __builtin_amdgcn_mfma_f32_16x16x32_f16(a[mf], b[nf], acc[mf][nf], 0, 0, 0);
    }

    // ---- epilogue in two 64-column halves ----
    const int cid = tid & 15;
    const int c4 = cid * 4;               // local col group within half
    const int rbase = tid >> 4;           // 0..15

    float rsacc[8];                       // per-thread row partials (both halves)
    #pragma unroll
    for (int it = 0; it < 8; ++it) rsacc[it] = 0.0f;

    #pragma unroll
    for (int half = 0; half < 2; ++half) {
        __syncthreads();   // previous half's T readers done
        if (wc == half) {
            #pragma unroll
            for (int mf = 0; mf < 4; ++mf)
                #pragma unroll
                for (int nf = 0; nf < 4; ++nf)
                    #pragma unroll
                    for (int r = 0; r < 4; ++r)
                        T[wr * 64 + mf * 16 + (lane >> 4) * 4 + r][nf * 16 + fr] = acc[mf][nf][r];
        }
        __syncthreads();

        f32x4 csum = (f32x4)0.0f;
        #pragma unroll
        for (int it = 0; it < 8; ++it) {
            const int r = rbase + it * 16;
            f32x4 L4 = *(const f32x4*)&T[r][c4];
            const size_t g = (size_t)(i0 + r) * N + j0 + half * 64 + c4;
            *(f32x4*)&logits[g] = L4;                       // plain store (L2)
            f32x4 u4 = __builtin_nontemporal_load((const f32x4*)&noise[g]);
            float rsum = 0.0f;
            unsigned q = 0;
            #pragma unroll
            for (int e = 0; e < 4; ++e) {
                float u = u4[e];
                float eps = fmaf(-0.9998f, u, 0.9999f);   // eps in [1e-4, 1-1e-4]
                float om  = fmaf( 0.9998f, u, 0.0001f);   // 1 - eps
                // v = sigmoid(log(eps)-log(1-eps)+L) = eps * rcp(eps + (1-eps)e^{-L})
                float ex = __expf(-L4[e]);
                float v = eps * __builtin_amdgcn_rcpf(fmaf(om, ex, eps));
                if (diag && r >= half * 64 + c4 + e) v = 0.0f;  // strict upper
                q |= ((unsigned)(int)rintf(v * 255.0f)) << (8 * e);
                rsum += v;
                csum[e] += v;
            }
            *(unsigned*)&vtile[r * 128 + half * 64 + c4] = q;   // plain store
            rsacc[it] += rsum;            // register accumulate
        }
        // col partials: butterfly across the 4 row-groups sharing each col
        #pragma unroll
        for (int e = 0; e < 4; ++e) {
            float cv = csum[e];
            cv += __shfl_xor(cv, 16);
            cv += __shfl_xor(cv, 32);
            if (lane < 16)
                cs2[w][half * 64 + lane * 4 + e] = cv;
        }

        if (!diag) {
            #pragma unroll
            for (int it = 0; it < 8; ++it) {
                const int idx = tid + it * 256;     // 0..2047
                const int c = idx >> 5;             // 0..63
                const int m4 = (idx & 31) * 4;
                f32x4 o;
                o[0] = T[m4 + 0][c]; o[1] = T[m4 + 1][c];
                o[2] = T[m4 + 2][c]; o[3] = T[m4 + 3][c];
                *(f32x4*)&logits[(size_t)(j0 + half * 64 + c) * N + i0 + m4] = o;  // plain
            }
        }
    }

    // row sums: 16 cid-owners of row r are 16 consecutive lanes of one wave
    #pragma unroll
    for (int it = 0; it < 8; ++it) {
        float rv = rsacc[it];
        rv += __shfl_xor(rv, 1);
        rv += __shfl_xor(rv, 2);
        rv += __shfl_xor(rv, 4);
        rv += __shfl_xor(rv, 8);
        if (cid == 0)
            rs1[rbase + it * 16] = rv;
    }

    __syncthreads();

    if (tid < 128) {
        const float rowsum = rs1[tid];
        const float colsum = cs2[0][tid] + cs2[1][tid] + cs2[2][tid] + cs2[3][tid];
        if (diag) {
            atomicAdd(&sums[i0 + tid], rowsum + colsum);
        } else {
            atomicAdd(&sums[i0 + tid], rowsum);
            atomicAdd(&sums[j0 + tid], colsum);
        }
    }
}

// ---------------------------------------------------------------------------
// k5: adj[i,j] = v_u8/255 * d_i * d_j (from compact vtile), mirror to [j,i],
// diagonal = d_i^2. d = rsqrt(sums) recomputed per block (L2-resident sums).
// T is [col][row] with 68-stride for 16B-aligned vectorized mirror stores.
// NT stores (pure 256 MiB streaming writer: plain stores thrash L2 -- R18
// measured +31 us; nt restored per R17 champion).
// ---------------------------------------------------------------------------
__global__ __launch_bounds__(256, 4) void k5_norm(
    const unsigned char* __restrict__ vws, float* __restrict__ adj,
    const float* __restrict__ sums)
{
    int ti, tj;
    const int t = (blockIdx.x & 7) * (NUPPER / 8) + (blockIdx.x >> 3);  // XCD swizzle
    tile_decode(t, ti, tj);
    const bool diag = (ti == tj);
    __shared__ float T[128][68];
    __shared__ float drow[128], dcol[128];
    const int tid = threadIdx.x;
    const int i0 = ti * 128, j0 = tj * 128;

    const unsigned char* __restrict__ vtile = vws + (size_t)t * (128 * 128);

    if (tid < 128) drow[tid] = rsqrtf(sums[i0 + tid]);
    else dcol[tid - 128] = rsqrtf(sums[j0 + tid - 128]);
    __syncthreads();

    const float inv255 = 1.0f / 255.0f;
    #pragma unroll 4
    for (int it = 0; it < 16; ++it) {
        int w = tid + it * 256;
        int m = w >> 5;
        int n4 = (w & 31) << 2;
        unsigned q = __builtin_nontemporal_load((const unsigned*)&vtile[m * 128 + n4]);
        float dm = drow[m];
        f32x4 o;
        o[0] = (float)(q & 255)         * inv255 * dm * dcol[n4 + 0];
        o[1] = (float)((q >> 8) & 255)  * inv255 * dm * dcol[n4 + 1];
        o[2] = (float)((q >> 16) & 255) * inv255 * dm * dcol[n4 + 2];
        o[3] = (float)(q >> 24)         * inv255 * dm * dcol[n4 + 3];
        __builtin_nontemporal_store(o, (f32x4*)&adj[(size_t)(i0 + m) * N + j0 + n4]);
        T[n4 + 0][m] = o[0]; T[n4 + 1][m] = o[1];
        T[n4 + 2][m] = o[2]; T[n4 + 3][m] = o[3];
    }
    __syncthreads();
    // mirror: adj[j0+c][i0+m4..m4+3] = T[c][m4..m4+3] (contiguous, 16B aligned)
    #pragma unroll 4
    for (int it = 0; it < 16; ++it) {
        int w = tid + it * 256;
        int c = w >> 5;
        int m4 = (w & 31) << 2;
        f32x4 o = *(const f32x4*)&T[c][m4];
        if (!diag) {
            __builtin_nontemporal_store(o, (f32x4*)&adj[(size_t)(j0 + c) * N + i0 + m4]);
        } else {
            #pragma unroll
            for (int e = 0; e < 4; ++e)
                if (m4 + e < c)
                    adj[(size_t)(j0 + c) * N + i0 + m4 + e] = o[e];
        }
    }
    if (diag && tid < 128) {
        float dm = drow[tid];
        adj[(size_t)(i0 + tid) * N + i0 + tid] = dm * dm;
    }
}

// ---------------------------------------------------------------------------
extern "C" void kernel_launch(void* const* d_in, const int* in_sizes, int n_in,
                              void* d_out, int out_size, void* d_ws, size_t ws_size,
                              hipStream_t stream)
{
    const float* h     = (const float*)d_in[0];
    const float* W1    = (const float*)d_in[1];
    const float* b1    = (const float*)d_in[2];
    const float* W2    = (const float*)d_in[3];
    const float* b2    = (const float*)d_in[4];
    const float* noise = (const float*)d_in[5];

    float* adj    = (float*)d_out;                 // output 0: adj_norm [N,N]
    float* logits = adj + (size_t)N * N;           // output 1: adj_logits [N,N]

    _Float16* Zf       = (_Float16*)d_ws;                      // 2 MiB
    unsigned char* vws = (unsigned char*)(Zf + (size_t)N * ZD);// 2080*16384 u8 = 34 MiB
    float* sums        = (float*)(vws + (size_t)NUPPER * 128 * 128); // [N]

    k1_mlp<<<256, 256, 0, stream>>>(h, W1, b1, W2, b2, Zf, sums);
    k3_main<<<NUPPER, 256, 0, stream>>>(Zf, noise, logits, vws, sums);
    k5_norm<<<NUPPER, 256, 0, stream>>>(vws, adj, sums);
}